// Round 1
// baseline (375.694 us; speedup 1.0000x reference)
//
#include <hip/hip_runtime.h>

typedef unsigned short u16;
typedef unsigned int u32;
typedef __attribute__((ext_vector_type(8))) short short8;
typedef __attribute__((ext_vector_type(4))) float f32x4;

// ---------- helpers ----------
__device__ inline u16 f2bf(float f) {           // round-to-nearest-even fp32->bf16
  u32 x = __float_as_uint(f);
  x += 0x7fff + ((x >> 16) & 1);
  return (u16)(x >> 16);
}
__device__ inline float bf2f(u16 h) {
  return __uint_as_float(((u32)h) << 16);
}
__device__ inline void gload16(const void* g, void* l) {
  // async global->LDS, 16B per lane (global_load_lds_dwordx4)
  __builtin_amdgcn_global_load_lds((const __attribute__((address_space(1))) u32*)g,
                                   (__attribute__((address_space(3))) u32*)l, 16, 0, 0);
}

// ---------- cast fp32 -> bf16 (4 elems/thread) ----------
__global__ void cast_f32_bf16(const float* __restrict__ src, u16* __restrict__ dst, size_t n) {
  size_t i = ((size_t)blockIdx.x * blockDim.x + threadIdx.x) * 4;
  if (i + 3 < n) {
    float4 v = *(const float4*)(src + i);
    ushort4 o;
    o.x = f2bf(v.x); o.y = f2bf(v.y); o.z = f2bf(v.z); o.w = f2bf(v.w);
    *(ushort4*)(dst + i) = o;
  }
}

// ---------- bf16 transpose: src[R][C] -> dst[C][R], per-batch via blockIdx.z ----------
__global__ void transpose_bf16(const u16* __restrict__ src, u16* __restrict__ dst, int R, int C) {
  __shared__ u16 tile[64][65];
  const size_t bofs = (size_t)blockIdx.z * R * C;
  const int r0 = blockIdx.y * 64, c0 = blockIdx.x * 64;
  const int tid = threadIdx.x;
#pragma unroll
  for (int p = 0; p < 16; ++p) {
    int idx = p * 256 + tid;
    int i = idx >> 6, j = idx & 63;
    tile[i][j] = src[bofs + (size_t)(r0 + i) * C + c0 + j];
  }
  __syncthreads();
#pragma unroll
  for (int p = 0; p < 16; ++p) {
    int idx = p * 256 + tid;
    int i = idx >> 6, j = idx & 63;   // i: row of dst tile (C-dim), j: col (R-dim)
    dst[bofs + (size_t)(c0 + i) * R + r0 + j] = tile[j][i];
  }
}

// ---------- NT GEMM: C[i,j] = sum_k A[i,k]*B[j,k], bf16 in, fp32 acc ----------
// MODE 0: + bias[col], store bf16            (Linear)
// MODE 1: exp(acc*scale), store bf16, atomic rowsum  (scores)
// MODE 2: acc * (1/rowsum[row]), store fp32  (P@V with fused normalize)
#define BM 128
#define BN 128
#define BK 32

template<int MODE>
__global__ __launch_bounds__(256, 2)
void gemm_nt(const u16* __restrict__ A, const u16* __restrict__ B,
             float* __restrict__ Cf, u16* __restrict__ Cb,
             const float* __restrict__ bias, float* __restrict__ rowsum,
             int M, int N, int K, float scale, long sA, long sB, long sC)
{
  __shared__ u16 As[BM * BK];
  __shared__ u16 Bs[BN * BK];

  const int z = blockIdx.z;
  A += (size_t)z * sA;
  B += (size_t)z * sB;
  if (MODE == 2) Cf += (size_t)z * sC; else Cb += (size_t)z * sC;
  if (MODE != 0) rowsum += (size_t)z * M;

  const int tid  = threadIdx.x;
  const int lane = tid & 63;
  const int wave = tid >> 6;
  const int wm = (wave >> 1) * 64;   // 2x2 waves of 64x64
  const int wn = (wave & 1) * 64;
  const int q = lane >> 4;           // k-quad for A/B frags; row-quad for C/D
  const int r = lane & 15;           // row (A) / col (B,C/D)

  const int mBase = blockIdx.y * BM;
  const int nBase = blockIdx.x * BN;

  // staging: tile is BMxBK bf16 = 8192B; 256 lanes x 16B = 4096B per issue -> 2 issues
  const int lo0 = tid * 16;          // byte offset into LDS tile, issue 0
  const int lo1 = lo0 + 4096;        // issue 1
  const int row0 = lo0 >> 6, kc0 = (lo0 & 63) >> 1;   // 64B (32 bf16) per row
  const int row1 = lo1 >> 6, kc1 = (lo1 & 63) >> 1;

  const u16* a0 = A + (size_t)(mBase + row0) * K + kc0;
  const u16* a1 = A + (size_t)(mBase + row1) * K + kc1;
  const u16* b0 = B + (size_t)(nBase + row0) * K + kc0;
  const u16* b1 = B + (size_t)(nBase + row1) * K + kc1;

  f32x4 acc[4][4] = {};

  for (int k0 = 0; k0 < K; k0 += BK) {
    gload16(a0 + k0, (char*)As + lo0);
    gload16(a1 + k0, (char*)As + lo1);
    gload16(b0 + k0, (char*)Bs + lo0);
    gload16(b1 + k0, (char*)Bs + lo1);
    __syncthreads();

    short8 af[4], bfr[4];
#pragma unroll
    for (int t = 0; t < 4; ++t) {
      af[t]  = *(const short8*)(As + (wm + t * 16 + r) * BK + q * 8);
      bfr[t] = *(const short8*)(Bs + (wn + t * 16 + r) * BK + q * 8);
    }
#pragma unroll
    for (int mi = 0; mi < 4; ++mi)
#pragma unroll
      for (int ni = 0; ni < 4; ++ni)
        acc[mi][ni] = __builtin_amdgcn_mfma_f32_16x16x32_bf16(af[mi], bfr[ni], acc[mi][ni], 0, 0, 0);
    __syncthreads();
  }

  // epilogue: C/D layout col = lane&15, row = (lane>>4)*4 + reg
  if (MODE == 0) {
#pragma unroll
    for (int mi = 0; mi < 4; ++mi) {
#pragma unroll
      for (int reg = 0; reg < 4; ++reg) {
        int rowg = mBase + wm + mi * 16 + q * 4 + reg;
#pragma unroll
        for (int ni = 0; ni < 4; ++ni) {
          int colg = nBase + wn + ni * 16 + r;
          float v = acc[mi][ni][reg] + bias[colg];
          Cb[(size_t)rowg * N + colg] = f2bf(v);
        }
      }
    }
  } else if (MODE == 1) {
#pragma unroll
    for (int mi = 0; mi < 4; ++mi) {
      float rs[4] = {0.f, 0.f, 0.f, 0.f};
#pragma unroll
      for (int ni = 0; ni < 4; ++ni) {
#pragma unroll
        for (int reg = 0; reg < 4; ++reg) {
          float e = __expf(acc[mi][ni][reg] * scale);
          u16 h = f2bf(e);
          rs[reg] += bf2f(h);   // sum the *rounded* values for numerator/denominator consistency
          int rowg = mBase + wm + mi * 16 + q * 4 + reg;
          int colg = nBase + wn + ni * 16 + r;
          Cb[(size_t)rowg * N + colg] = h;
        }
      }
#pragma unroll
      for (int reg = 0; reg < 4; ++reg) {
        float v = rs[reg];
        v += __shfl_xor(v, 1);
        v += __shfl_xor(v, 2);
        v += __shfl_xor(v, 4);
        v += __shfl_xor(v, 8);
        if (r == 0)
          atomicAdd(&rowsum[mBase + wm + mi * 16 + q * 4 + reg], v);
      }
    }
  } else {
#pragma unroll
    for (int mi = 0; mi < 4; ++mi) {
#pragma unroll
      for (int reg = 0; reg < 4; ++reg) {
        int rowg = mBase + wm + mi * 16 + q * 4 + reg;
        float inv = 1.0f / rowsum[rowg];
#pragma unroll
        for (int ni = 0; ni < 4; ++ni) {
          int colg = nBase + wn + ni * 16 + r;
          Cf[(size_t)rowg * N + colg] = acc[mi][ni][reg] * inv;
        }
      }
    }
  }
}

// ---------- launch ----------
// Problem constants: B=8, N=2048, E=O=1024
extern "C" void kernel_launch(void* const* d_in, const int* in_sizes, int n_in,
                              void* d_out, int out_size, void* d_ws, size_t ws_size,
                              hipStream_t stream) {
  const float* embd = (const float*)d_in[0];   // [8,2048,1024]
  const float* W    = (const float*)d_in[1];   // [1024,1024]
  const float* bias = (const float*)d_in[2];   // [1024]
  float* out = (float*)d_out;                  // [8,2048,1024] fp32

  char* ws = (char*)d_ws;
  // layout (bytes). embd_b/W_b are dead after GEMM1 and alias the P region.
  u16* P_b    = (u16*)(ws + 0);            // 8*2048*2048*2 = 67108864
  u16* embd_b = (u16*)(ws + 0);            // 33554432 (aliases P, dead before K2)
  u16* W_b    = (u16*)(ws + 33554432);     // 2097152  (aliases P, dead before K2)
  u16* c_b    = (u16*)(ws + 67108864);     // 33554432
  u16* cT_b   = (u16*)(ws + 100663296);    // 33554432
  float* rowsum = (float*)(ws + 134217728);// 16384*4 = 65536   (total 128.06 MB)

  // 1) casts
  cast_f32_bf16<<<16384, 256, 0, stream>>>(embd, embd_b, (size_t)16777216);
  cast_f32_bf16<<<1024, 256, 0, stream>>>(W, W_b, (size_t)1048576);

  // 2) c = embd @ W^T + b : M=16384, N=1024, K=1024
  gemm_nt<0><<<dim3(8, 128, 1), 256, 0, stream>>>(
      embd_b, W_b, nullptr, c_b, bias, nullptr,
      16384, 1024, 1024, 0.f, 0, 0, 0);

  // 3) cT[b][o][n] = c[b][n][o]
  transpose_bf16<<<dim3(16, 32, 8), 256, 0, stream>>>(c_b, cT_b, 2048, 1024);

  // 4) rowsum = 0
  hipMemsetAsync(rowsum, 0, 16384 * sizeof(float), stream);

  // 5) P = exp(c c^T / 32) (unnormalized, bf16) + rowsums. per batch M=N=2048, K=1024
  gemm_nt<1><<<dim3(16, 16, 8), 256, 0, stream>>>(
      c_b, c_b, nullptr, P_b, nullptr, rowsum,
      2048, 2048, 1024, 0.03125f, 2048L * 1024, 2048L * 1024, 2048L * 2048);

  // 6) O = (P @ V) / rowsum : per batch M=2048, N=1024, K=2048; B = cT
  gemm_nt<2><<<dim3(8, 16, 8), 256, 0, stream>>>(
      P_b, cT_b, out, nullptr, nullptr, rowsum,
      2048, 1024, 2048, 0.f, 2048L * 2048, 2048L * 1024, 2048L * 1024);
}

// Round 2
// 345.094 us; speedup vs baseline: 1.0887x; 1.0887x over previous
//
#include <hip/hip_runtime.h>

typedef unsigned short u16;
typedef unsigned int u32;
typedef __attribute__((ext_vector_type(8))) short short8;
typedef __attribute__((ext_vector_type(4))) float f32x4;

// ---------- helpers ----------
__device__ inline u16 f2bf(float f) {           // round-to-nearest-even fp32->bf16
  u32 x = __float_as_uint(f);
  x += 0x7fff + ((x >> 16) & 1);
  return (u16)(x >> 16);
}
__device__ inline float bf2f(u16 h) {
  return __uint_as_float(((u32)h) << 16);
}
__device__ inline void gload16(const void* g, void* l) {
  // async global->LDS, 16B per lane (global_load_lds_dwordx4)
  __builtin_amdgcn_global_load_lds((const __attribute__((address_space(1))) u32*)g,
                                   (__attribute__((address_space(3))) u32*)l, 16, 0, 0);
}

// swizzled 128x128 bf16 tile in LDS: row = 128 u16 (256B = 16 granules of 16B).
// granule index XORed with (row>>3)&7 so column (scalar) reads spread banks.
__device__ inline int stile_off(int rg, int cg) {
  return rg * 128 + ((((cg >> 3) ^ ((rg >> 3) & 7)) << 3)) + (cg & 7);
}

// ---------- fused cast fp32 -> bf16 for embd and W ----------
__global__ void cast_all(const float* __restrict__ embd, const float* __restrict__ W,
                         u16* __restrict__ embd_b, u16* __restrict__ W_b) {
  const float* src; u16* dst; size_t i;
  if (blockIdx.x < 16384) {
    src = embd; dst = embd_b;
    i = ((size_t)blockIdx.x * 256 + threadIdx.x) * 4;
  } else {
    src = W; dst = W_b;
    i = ((size_t)(blockIdx.x - 16384) * 256 + threadIdx.x) * 4;
  }
  float4 v = *(const float4*)(src + i);
  ushort4 o;
  o.x = f2bf(v.x); o.y = f2bf(v.y); o.z = f2bf(v.z); o.w = f2bf(v.w);
  *(ushort4*)(dst + i) = o;
}

// ---------- NT GEMM: C[i,j] = sum_k A[i,k]*B[j,k], bf16 in, fp32 acc ----------
// MODE 0: + bias[col], store bf16 C AND bf16 C^T (fused transpose)   (Linear)
// MODE 1: triangular grid (S symmetric): exp(acc*scale), store tile + mirrored
//         tile, atomic rowsums (direct rows + mirror rows via colsums)
// MODE 2: acc * (1/rowsum[row]), store fp32 coalesced via LDS staging (P@V)
#define BM 128
#define BN 128
#define BK 32

template<int MODE>
__global__ __launch_bounds__(256, 2)
void gemm_nt(const u16* __restrict__ A, const u16* __restrict__ B,
             float* __restrict__ Cf, u16* __restrict__ Cb, u16* __restrict__ CT,
             const float* __restrict__ bias, float* __restrict__ rowsum,
             int M, int N, int K, float scale, long sA, long sB, long sC)
{
  // union: K-loop staging (As 8KB | Bs 8KB) vs epilogue tile (32KB)
  __shared__ __align__(16) char smem[32768];
  u16* As = (u16*)smem;            // BM*BK u16
  u16* Bs = As + BM * BK;          // BN*BK u16
  u16* stile = (u16*)smem;         // 128*128 swizzled (MODE 0/1)
  float* stf = (float*)smem;       // 64*128 f32 (MODE 2)

  const int z = blockIdx.z;
  A += (size_t)z * sA;
  B += (size_t)z * sB;
  if (MODE == 2) Cf += (size_t)z * sC; else Cb += (size_t)z * sC;
  if (MODE != 0) rowsum += (size_t)z * M;

  const int tid  = threadIdx.x;
  const int lane = tid & 63;
  const int wave = tid >> 6;
  const int wm = (wave >> 1) * 64;   // 2x2 waves of 64x64
  const int wn = (wave & 1) * 64;
  const int q = lane >> 4;           // k-quad for A/B frags; row-quad for C/D
  const int r = lane & 15;           // row (A) / col (B,C/D)

  int mBase, nBase, bi = 0, bj = 0;
  if (MODE == 1) {
    // triangular decode: blockIdx.x in [0, nb*(nb+1)/2), pairs (bi <= bj)
    int t = blockIdx.x, row = 0;
    const int nb = N >> 7;
    while (t >= nb - row) { t -= nb - row; ++row; }
    bi = row; bj = row + t;
    mBase = bi * BM; nBase = bj * BN;
  } else {
    mBase = blockIdx.y * BM;
    nBase = blockIdx.x * BN;
  }

  // staging: tile is BMxBK bf16 = 8192B; 256 lanes x 16B = 4096B per issue -> 2 issues
  const int lo0 = tid * 16;
  const int lo1 = lo0 + 4096;
  const int row0 = lo0 >> 6, kc0 = (lo0 & 63) >> 1;   // 64B (32 bf16) per row
  const int row1 = lo1 >> 6, kc1 = (lo1 & 63) >> 1;

  const u16* a0 = A + (size_t)(mBase + row0) * K + kc0;
  const u16* a1 = A + (size_t)(mBase + row1) * K + kc1;
  const u16* b0 = B + (size_t)(nBase + row0) * K + kc0;
  const u16* b1 = B + (size_t)(nBase + row1) * K + kc1;

  f32x4 acc[4][4] = {};

  for (int k0 = 0; k0 < K; k0 += BK) {
    gload16(a0 + k0, (char*)As + lo0);
    gload16(a1 + k0, (char*)As + lo1);
    gload16(b0 + k0, (char*)Bs + lo0);
    gload16(b1 + k0, (char*)Bs + lo1);
    __syncthreads();

    short8 af[4], bfr[4];
#pragma unroll
    for (int t = 0; t < 4; ++t) {
      af[t]  = *(const short8*)(As + (wm + t * 16 + r) * BK + q * 8);
      bfr[t] = *(const short8*)(Bs + (wn + t * 16 + r) * BK + q * 8);
    }
#pragma unroll
    for (int mi = 0; mi < 4; ++mi)
#pragma unroll
      for (int ni = 0; ni < 4; ++ni)
        acc[mi][ni] = __builtin_amdgcn_mfma_f32_16x16x32_bf16(af[mi], bfr[ni], acc[mi][ni], 0, 0, 0);
    __syncthreads();
  }

  // C/D layout: col = lane&15 (r), row = (lane>>4)*4 + reg  (q*4+reg)

  if (MODE == 0) {
    float bv[4];
#pragma unroll
    for (int ni = 0; ni < 4; ++ni) bv[ni] = bias[nBase + wn + ni * 16 + r];
#pragma unroll
    for (int mi = 0; mi < 4; ++mi)
#pragma unroll
      for (int ni = 0; ni < 4; ++ni)
#pragma unroll
        for (int reg = 0; reg < 4; ++reg) {
          int rl = wm + mi * 16 + q * 4 + reg;
          int cl = wn + ni * 16 + r;
          stile[stile_off(rl, cl)] = f2bf(acc[mi][ni][reg] + bv[ni]);
        }
    __syncthreads();
    // c write: coalesced rows
    {
      const int z1 = mBase >> 11;           // batch of this row-tile
      const int n0 = mBase & 2047;
      u16* ctb = CT + (size_t)z1 * 1024 * 2048;
#pragma unroll
      for (int rnd = 0; rnd < 8; ++rnd) {
        int idx = rnd * 256 + tid;
        int ch = idx & 15, n = idx >> 4;
        short8 v = *(const short8*)(stile + n * 128 + ((ch ^ ((n >> 3) & 7)) << 3));
        *(short8*)(Cb + (size_t)(mBase + n) * N + nBase + ch * 8) = v;
      }
      // cT write: column reads (scalar, swizzle-spread), coalesced stores
#pragma unroll
      for (int rnd = 0; rnd < 8; ++rnd) {
        int idx = rnd * 256 + tid;
        int ch = idx & 15, cc = idx >> 4;
        short8 v;
#pragma unroll
        for (int j = 0; j < 8; ++j) v[j] = (short)stile[stile_off(ch * 8 + j, cc)];
        *(short8*)(ctb + (size_t)(nBase + cc) * 2048 + n0 + ch * 8) = v;
      }
    }
  } else if (MODE == 1) {
    const bool mirror = (bi != bj);
    float colacc[4] = {0.f, 0.f, 0.f, 0.f};
#pragma unroll
    for (int mi = 0; mi < 4; ++mi) {
      float rs[4] = {0.f, 0.f, 0.f, 0.f};
#pragma unroll
      for (int ni = 0; ni < 4; ++ni)
#pragma unroll
        for (int reg = 0; reg < 4; ++reg) {
          float e = __expf(acc[mi][ni][reg] * scale);
          u16 h = f2bf(e);
          float f = bf2f(h);      // rounded value for num/denom consistency
          rs[reg] += f;
          if (mirror) colacc[ni] += f;
          stile[stile_off(wm + mi * 16 + q * 4 + reg, wn + ni * 16 + r)] = h;
        }
      // direct rowsums: reduce over r (cols) within q-group
#pragma unroll
      for (int reg = 0; reg < 4; ++reg) {
        float v = rs[reg];
        v += __shfl_xor(v, 1);
        v += __shfl_xor(v, 2);
        v += __shfl_xor(v, 4);
        v += __shfl_xor(v, 8);
        if (r == 0)
          atomicAdd(&rowsum[mBase + wm + mi * 16 + q * 4 + reg], v);
      }
    }
    if (mirror) {
      // mirror rowsums = column sums: reduce over q (rows)
#pragma unroll
      for (int ni = 0; ni < 4; ++ni) {
        float v = colacc[ni];
        v += __shfl_xor(v, 16);
        v += __shfl_xor(v, 32);
        if (q == 0)
          atomicAdd(&rowsum[nBase + wn + ni * 16 + r], v);
      }
    }
    __syncthreads();
    // direct tile write: coalesced rows
#pragma unroll
    for (int rnd = 0; rnd < 8; ++rnd) {
      int idx = rnd * 256 + tid;
      int ch = idx & 15, n = idx >> 4;
      short8 v = *(const short8*)(stile + n * 128 + ((ch ^ ((n >> 3) & 7)) << 3));
      *(short8*)(Cb + (size_t)(mBase + n) * N + nBase + ch * 8) = v;
    }
    if (mirror) {
      // mirrored tile write: column reads, coalesced stores to block (bj,bi)
#pragma unroll
      for (int rnd = 0; rnd < 8; ++rnd) {
        int idx = rnd * 256 + tid;
        int ch = idx & 15, cc = idx >> 4;
        short8 v;
#pragma unroll
        for (int j = 0; j < 8; ++j) v[j] = (short)stile[stile_off(ch * 8 + j, cc)];
        *(short8*)(Cb + (size_t)(nBase + cc) * N + mBase + ch * 8) = v;
      }
    }
  } else {
    // MODE 2: normalize + fp32 store, staged through LDS in two 64-row phases
#pragma unroll
    for (int p = 0; p < 2; ++p) {
      if ((wave >> 1) == p) {
#pragma unroll
        for (int mi = 0; mi < 4; ++mi)
#pragma unroll
          for (int reg = 0; reg < 4; ++reg) {
            int lr = mi * 16 + q * 4 + reg;
            float inv = 1.0f / rowsum[mBase + wm + lr];
#pragma unroll
            for (int ni = 0; ni < 4; ++ni)
              stf[lr * 128 + wn + ni * 16 + r] = acc[mi][ni][reg] * inv;
          }
      }
      __syncthreads();
#pragma unroll
      for (int rnd = 0; rnd < 8; ++rnd) {
        int idx = rnd * 256 + tid;
        int n = idx >> 5, ch = idx & 31;
        float4 v = *(const float4*)(stf + n * 128 + ch * 4);
        *(float4*)(Cf + (size_t)(mBase + p * 64 + n) * N + nBase + ch * 4) = v;
      }
      __syncthreads();
    }
  }
}

// ---------- launch ----------
// Problem constants: B=8, N=2048, E=O=1024
extern "C" void kernel_launch(void* const* d_in, const int* in_sizes, int n_in,
                              void* d_out, int out_size, void* d_ws, size_t ws_size,
                              hipStream_t stream) {
  const float* embd = (const float*)d_in[0];   // [8,2048,1024]
  const float* W    = (const float*)d_in[1];   // [1024,1024]
  const float* bias = (const float*)d_in[2];   // [1024]
  float* out = (float*)d_out;                  // [8,2048,1024] fp32

  char* ws = (char*)d_ws;
  u16* P_b    = (u16*)(ws + 0);            // 8*2048*2048*2 = 67108864
  u16* embd_b = (u16*)(ws + 0);            // 33554432 (aliases P, dead before GEMM2)
  u16* W_b    = (u16*)(ws + 33554432);     // 2097152  (aliases P, dead before GEMM2)
  u16* c_b    = (u16*)(ws + 67108864);     // 33554432
  u16* cT_b   = (u16*)(ws + 100663296);    // 33554432
  float* rowsum = (float*)(ws + 134217728);// 16384*4

  // 1) casts (fused)
  cast_all<<<17408, 256, 0, stream>>>(embd, W, embd_b, W_b);

  // 2) c = embd @ W^T + b, plus fused c^T : M=16384, N=1024, K=1024
  gemm_nt<0><<<dim3(8, 128, 1), 256, 0, stream>>>(
      embd_b, W_b, nullptr, c_b, cT_b, bias, nullptr,
      16384, 1024, 1024, 0.f, 0, 0, 0);

  // 3) rowsum = 0
  hipMemsetAsync(rowsum, 0, 16384 * sizeof(float), stream);

  // 4) P = exp(c c^T / 32) unnormalized bf16, triangular (S symmetric) + rowsums
  //    per batch M=N=2048, K=1024; 136 block-pairs
  gemm_nt<1><<<dim3(136, 1, 8), 256, 0, stream>>>(
      c_b, c_b, nullptr, P_b, nullptr, nullptr, rowsum,
      2048, 2048, 1024, 0.03125f, 2048L * 1024, 2048L * 1024, 2048L * 2048);

  // 5) O = (P @ c) / rowsum : per batch M=2048, N=1024, K=2048; B = cT
  gemm_nt<2><<<dim3(8, 16, 8), 256, 0, stream>>>(
      P_b, cT_b, out, nullptr, nullptr, nullptr, rowsum,
      2048, 1024, 2048, 0.f, 2048L * 2048, 2048L * 1024, 2048L * 1024);
}

// Round 3
// 315.432 us; speedup vs baseline: 1.1910x; 1.0940x over previous
//
#include <hip/hip_runtime.h>

typedef unsigned short u16;
typedef unsigned int u32;
typedef __attribute__((ext_vector_type(8))) short short8;
typedef __attribute__((ext_vector_type(4))) float f32x4;

// ---------- helpers ----------
__device__ inline u16 f2bf(float f) {           // round-to-nearest-even fp32->bf16
  u32 x = __float_as_uint(f);
  x += 0x7fff + ((x >> 16) & 1);
  return (u16)(x >> 16);
}
__device__ inline float bf2f(u16 h) {
  return __uint_as_float(((u32)h) << 16);
}
__device__ inline void gload16(const void* g, void* l) {
  // async global->LDS, 16B per lane (global_load_lds_dwordx4)
  __builtin_amdgcn_global_load_lds((const __attribute__((address_space(1))) u32*)g,
                                   (__attribute__((address_space(3))) u32*)l, 16, 0, 0);
}

// swizzled 128x128 bf16 tile in LDS: row = 128 u16 (256B = 16 granules of 16B).
// granule index XORed with (row>>3)&7 so column (scalar) reads spread banks.
__device__ inline int stile_off(int rg, int cg) {
  return rg * 128 + ((((cg >> 3) ^ ((rg >> 3) & 7)) << 3)) + (cg & 7);
}

// ---------- fused cast fp32 -> bf16 for embd and W ----------
__global__ void cast_all(const float* __restrict__ embd, const float* __restrict__ W,
                         u16* __restrict__ embd_b, u16* __restrict__ W_b) {
  const float* src; u16* dst; size_t i;
  if (blockIdx.x < 16384) {
    src = embd; dst = embd_b;
    i = ((size_t)blockIdx.x * 256 + threadIdx.x) * 4;
  } else {
    src = W; dst = W_b;
    i = ((size_t)(blockIdx.x - 16384) * 256 + threadIdx.x) * 4;
  }
  float4 v = *(const float4*)(src + i);
  ushort4 o;
  o.x = f2bf(v.x); o.y = f2bf(v.y); o.z = f2bf(v.z); o.w = f2bf(v.w);
  *(ushort4*)(dst + i) = o;
}

// ---------- NT GEMM: C[i,j] = sum_k A[i,k]*B[j,k], bf16 in, fp32 acc ----------
// MODE 0: + bias[col], store bf16 C AND bf16 C^T (fused transpose)   (Linear)
//         grid (nblk, mblk, 1)
// MODE 1: triangular grid (S symmetric): exp(acc*scale), store tile + mirrored
//         tile, atomic rowsums. grid (batch, pair, 1) -> XCD = batch (flat%8)
// MODE 2: acc * (1/rowsum[row]), store fp32 coalesced via LDS staging (P@V)
//         grid (batch, mblk*8+nblk, 1) -> XCD = batch, n-fastest for A reuse
#define BM 128
#define BN 128
#define BK 32

template<int MODE>
__global__ __launch_bounds__(256, 2)
void gemm_nt(const u16* __restrict__ A, const u16* __restrict__ B,
             float* __restrict__ Cf, u16* __restrict__ Cb, u16* __restrict__ CT,
             const float* __restrict__ bias, float* __restrict__ rowsum,
             int M, int N, int K, float scale, long sA, long sB, long sC)
{
  // union: K-loop staging (As 8KB | Bs 8KB) vs epilogue tile (32KB)
  __shared__ __align__(16) char smem[32768];
  u16* As = (u16*)smem;            // BM*BK u16
  u16* Bs = As + BM * BK;          // BN*BK u16
  u16* stile = (u16*)smem;         // 128*128 swizzled (MODE 0/1)
  float* stf = (float*)smem;       // 64*128 f32 (MODE 2)

  // ---- block index decode (XCD-affinity swizzles for MODE 1/2) ----
  int z, mBase, nBase, bi = 0, bj = 0;
  if (MODE == 0) {
    z = 0;
    mBase = blockIdx.y * BM;
    nBase = blockIdx.x * BN;
  } else if (MODE == 1) {
    z = blockIdx.x;                 // flat%8 == batch -> one XCD per batch
    int t = blockIdx.y, row = 0;
    const int nb = N >> 7;
    while (t >= nb - row) { t -= nb - row; ++row; }
    bi = row; bj = row + t;
    mBase = bi * BM; nBase = bj * BN;
  } else {
    z = blockIdx.x;                 // flat%8 == batch
    nBase = (blockIdx.y & 7) * BN;  // n fastest within batch -> A-row-tile reuse
    mBase = (blockIdx.y >> 3) * BM;
  }

  A += (size_t)z * sA;
  B += (size_t)z * sB;
  if (MODE == 2) Cf += (size_t)z * sC; else Cb += (size_t)z * sC;
  if (MODE != 0) rowsum += (size_t)z * M;

  const int tid  = threadIdx.x;
  const int lane = tid & 63;
  const int wave = tid >> 6;
  const int wm = (wave >> 1) * 64;   // 2x2 waves of 64x64
  const int wn = (wave & 1) * 64;
  const int q = lane >> 4;           // k-quad for A/B frags; row-quad for C/D
  const int r = lane & 15;           // row (A) / col (B,C/D)

  // staging: tile is BMxBK bf16 = 8192B; 256 lanes x 16B = 4096B per issue -> 2 issues
  const int lo0 = tid * 16;
  const int lo1 = lo0 + 4096;
  const int row0 = lo0 >> 6, kc0 = (lo0 & 63) >> 1;   // 64B (32 bf16) per row
  const int row1 = lo1 >> 6, kc1 = (lo1 & 63) >> 1;

  const u16* a0 = A + (size_t)(mBase + row0) * K + kc0;
  const u16* a1 = A + (size_t)(mBase + row1) * K + kc1;
  const u16* b0 = B + (size_t)(nBase + row0) * K + kc0;
  const u16* b1 = B + (size_t)(nBase + row1) * K + kc1;

  f32x4 acc[4][4] = {};

  for (int k0 = 0; k0 < K; k0 += BK) {
    gload16(a0 + k0, (char*)As + lo0);
    gload16(a1 + k0, (char*)As + lo1);
    gload16(b0 + k0, (char*)Bs + lo0);
    gload16(b1 + k0, (char*)Bs + lo1);
    __syncthreads();

    short8 af[4], bfr[4];
#pragma unroll
    for (int t = 0; t < 4; ++t) {
      af[t]  = *(const short8*)(As + (wm + t * 16 + r) * BK + q * 8);
      bfr[t] = *(const short8*)(Bs + (wn + t * 16 + r) * BK + q * 8);
    }
#pragma unroll
    for (int mi = 0; mi < 4; ++mi)
#pragma unroll
      for (int ni = 0; ni < 4; ++ni)
        acc[mi][ni] = __builtin_amdgcn_mfma_f32_16x16x32_bf16(af[mi], bfr[ni], acc[mi][ni], 0, 0, 0);
    __syncthreads();
  }

  // C/D layout: col = lane&15 (r), row = (lane>>4)*4 + reg  (q*4+reg)

  if (MODE == 0) {
    float bv[4];
#pragma unroll
    for (int ni = 0; ni < 4; ++ni) bv[ni] = bias[nBase + wn + ni * 16 + r];
#pragma unroll
    for (int mi = 0; mi < 4; ++mi)
#pragma unroll
      for (int ni = 0; ni < 4; ++ni)
#pragma unroll
        for (int reg = 0; reg < 4; ++reg) {
          int rl = wm + mi * 16 + q * 4 + reg;
          int cl = wn + ni * 16 + r;
          stile[stile_off(rl, cl)] = f2bf(acc[mi][ni][reg] + bv[ni]);
        }
    __syncthreads();
    // c write: coalesced rows
    {
      const int z1 = mBase >> 11;           // batch of this row-tile
      const int n0 = mBase & 2047;
      u16* ctb = CT + (size_t)z1 * 1024 * 2048;
#pragma unroll
      for (int rnd = 0; rnd < 8; ++rnd) {
        int idx = rnd * 256 + tid;
        int ch = idx & 15, n = idx >> 4;
        short8 v = *(const short8*)(stile + n * 128 + ((ch ^ ((n >> 3) & 7)) << 3));
        *(short8*)(Cb + (size_t)(mBase + n) * N + nBase + ch * 8) = v;
      }
      // cT write: column reads (scalar, swizzle-spread), coalesced stores
#pragma unroll
      for (int rnd = 0; rnd < 8; ++rnd) {
        int idx = rnd * 256 + tid;
        int ch = idx & 15, cc = idx >> 4;
        short8 v;
#pragma unroll
        for (int j = 0; j < 8; ++j) v[j] = (short)stile[stile_off(ch * 8 + j, cc)];
        *(short8*)(ctb + (size_t)(nBase + cc) * 2048 + n0 + ch * 8) = v;
      }
    }
  } else if (MODE == 1) {
    const bool mirror = (bi != bj);
    float colacc[4] = {0.f, 0.f, 0.f, 0.f};
#pragma unroll
    for (int mi = 0; mi < 4; ++mi) {
      float rs[4] = {0.f, 0.f, 0.f, 0.f};
#pragma unroll
      for (int ni = 0; ni < 4; ++ni)
#pragma unroll
        for (int reg = 0; reg < 4; ++reg) {
          float e = __expf(acc[mi][ni][reg] * scale);
          u16 h = f2bf(e);
          float f = bf2f(h);      // rounded value for num/denom consistency
          rs[reg] += f;
          if (mirror) colacc[ni] += f;
          stile[stile_off(wm + mi * 16 + q * 4 + reg, wn + ni * 16 + r)] = h;
        }
      // direct rowsums: reduce over r (cols) within q-group
#pragma unroll
      for (int reg = 0; reg < 4; ++reg) {
        float v = rs[reg];
        v += __shfl_xor(v, 1);
        v += __shfl_xor(v, 2);
        v += __shfl_xor(v, 4);
        v += __shfl_xor(v, 8);
        if (r == 0)
          atomicAdd(&rowsum[mBase + wm + mi * 16 + q * 4 + reg], v);
      }
    }
    if (mirror) {
      // mirror rowsums = column sums: reduce over q (rows)
#pragma unroll
      for (int ni = 0; ni < 4; ++ni) {
        float v = colacc[ni];
        v += __shfl_xor(v, 16);
        v += __shfl_xor(v, 32);
        if (q == 0)
          atomicAdd(&rowsum[nBase + wn + ni * 16 + r], v);
      }
    }
    __syncthreads();
    // direct tile write: coalesced rows
#pragma unroll
    for (int rnd = 0; rnd < 8; ++rnd) {
      int idx = rnd * 256 + tid;
      int ch = idx & 15, n = idx >> 4;
      short8 v = *(const short8*)(stile + n * 128 + ((ch ^ ((n >> 3) & 7)) << 3));
      *(short8*)(Cb + (size_t)(mBase + n) * N + nBase + ch * 8) = v;
    }
    if (mirror) {
      // mirrored tile write: column reads, coalesced stores to block (bj,bi)
#pragma unroll
      for (int rnd = 0; rnd < 8; ++rnd) {
        int idx = rnd * 256 + tid;
        int ch = idx & 15, cc = idx >> 4;
        short8 v;
#pragma unroll
        for (int j = 0; j < 8; ++j) v[j] = (short)stile[stile_off(ch * 8 + j, cc)];
        *(short8*)(Cb + (size_t)(nBase + cc) * N + mBase + ch * 8) = v;
      }
    }
  } else {
    // MODE 2: normalize + fp32 store, staged through LDS in two 64-row phases
#pragma unroll
    for (int p = 0; p < 2; ++p) {
      if ((wave >> 1) == p) {
#pragma unroll
        for (int mi = 0; mi < 4; ++mi)
#pragma unroll
          for (int reg = 0; reg < 4; ++reg) {
            int lr = mi * 16 + q * 4 + reg;
            float inv = 1.0f / rowsum[mBase + wm + lr];
#pragma unroll
            for (int ni = 0; ni < 4; ++ni)
              stf[lr * 128 + wn + ni * 16 + r] = acc[mi][ni][reg] * inv;
          }
      }
      __syncthreads();
#pragma unroll
      for (int rnd = 0; rnd < 8; ++rnd) {
        int idx = rnd * 256 + tid;
        int n = idx >> 5, ch = idx & 31;
        float4 v = *(const float4*)(stf + n * 128 + ch * 4);
        *(float4*)(Cf + (size_t)(mBase + p * 64 + n) * N + nBase + ch * 4) = v;
      }
      __syncthreads();
    }
  }
}

// ---------- launch ----------
// Problem constants: B=8, N=2048, E=O=1024
extern "C" void kernel_launch(void* const* d_in, const int* in_sizes, int n_in,
                              void* d_out, int out_size, void* d_ws, size_t ws_size,
                              hipStream_t stream) {
  const float* embd = (const float*)d_in[0];   // [8,2048,1024]
  const float* W    = (const float*)d_in[1];   // [1024,1024]
  const float* bias = (const float*)d_in[2];   // [1024]
  float* out = (float*)d_out;                  // [8,2048,1024] fp32

  char* ws = (char*)d_ws;
  u16* P_b    = (u16*)(ws + 0);            // 8*2048*2048*2 = 67108864
  u16* embd_b = (u16*)(ws + 0);            // 33554432 (aliases P, dead before GEMM2)
  u16* W_b    = (u16*)(ws + 33554432);     // 2097152  (aliases P, dead before GEMM2)
  u16* c_b    = (u16*)(ws + 67108864);     // 33554432
  u16* cT_b   = (u16*)(ws + 100663296);    // 33554432
  float* rowsum = (float*)(ws + 134217728);// 16384*4

  // 1) casts (fused)
  cast_all<<<17408, 256, 0, stream>>>(embd, W, embd_b, W_b);

  // 2) c = embd @ W^T + b, plus fused c^T : M=16384, N=1024, K=1024
  gemm_nt<0><<<dim3(8, 128, 1), 256, 0, stream>>>(
      embd_b, W_b, nullptr, c_b, cT_b, bias, nullptr,
      16384, 1024, 1024, 0.f, 0, 0, 0);

  // 3) rowsum = 0
  hipMemsetAsync(rowsum, 0, 16384 * sizeof(float), stream);

  // 4) P = exp(c c^T / 32) unnormalized bf16, triangular (S symmetric) + rowsums
  //    grid (batch=8, pair=136): flat%8==batch -> per-XCD c residency (4 MB)
  gemm_nt<1><<<dim3(8, 136, 1), 256, 0, stream>>>(
      c_b, c_b, nullptr, P_b, nullptr, nullptr, rowsum,
      2048, 2048, 1024, 0.03125f, 2048L * 1024, 2048L * 1024, 2048L * 2048);

  // 5) O = (P @ c) / rowsum : per batch M=2048, N=1024, K=2048; B = cT
  //    grid (batch=8, mblk*8+nblk=128): per-XCD batch affinity, n-fastest
  gemm_nt<2><<<dim3(8, 128, 1), 256, 0, stream>>>(
      P_b, cT_b, out, nullptr, nullptr, nullptr, rowsum,
      2048, 1024, 2048, 0.f, 2048L * 2048, 2048L * 1024, 2048L * 1024);
}